// Round 3
// baseline (2755.445 us; speedup 1.0000x reference)
//
#include <hip/hip_runtime.h>
#include <math.h>

// ---------------------------------------------------------------------------
// Generic GEMM: out[r][j] = dot(row_r, W[j][0:K]) + bias[j], j in [0,150)
// row_r = emb[idx[r]] (gather mode) or src + r*K (direct mode, idx==null)
// Block: 256 threads, 64 rows. Thread: 2 rows x 19 strided j's.
// ---------------------------------------------------------------------------
__global__ __launch_bounds__(256) void k_gemm150(
    const float* __restrict__ W, const float* __restrict__ bias,
    const float* __restrict__ src, const int* __restrict__ idx,
    float* __restrict__ out, int K)
{
    __shared__ float smem[9600];              // eT[64][44] | wT[152][44], reused as outT[64][150]
    __shared__ const float* rptr[64];
    float* eT = smem;                          // 64*44 = 2816
    float* wT = smem + 64 * 44;                // 152*44 = 6688 (rows 150..151 garbage, never stored)
    const int t = threadIdx.x;
    const long blockR = (long)blockIdx.x * 64;

    if (t < 64) {
        long gr = blockR + t;
        rptr[t] = src + (size_t)(idx ? idx[gr] : gr) * (size_t)K;
    }

    const int r0 = t & 31;
    const int r1 = r0 + 32;
    const int jg = t >> 5;

    float acc0[19], acc1[19];
#pragma unroll
    for (int i = 0; i < 19; ++i) {
        int j = jg + 8 * i;
        float b = (j < 150) ? bias[j] : 0.f;
        acc0[i] = b; acc1[i] = b;
    }

    const int nch = K / 40;
    for (int c = 0; c < nch; ++c) {
        const int k0 = c * 40;
        __syncthreads();
        for (int fid = t; fid < 640; fid += 256) {        // stage src tile 64x40
            int r = fid / 10, ko = (fid % 10) * 4;
            *(float4*)&eT[r * 44 + ko] = *(const float4*)(rptr[r] + k0 + ko);
        }
        for (int fid = t; fid < 1500; fid += 256) {       // stage W tile 150x40
            int r = fid / 10, ko = (fid % 10) * 4;
            *(float4*)&wT[r * 44 + ko] = *(const float4*)(W + (size_t)r * K + k0 + ko);
        }
        __syncthreads();
#pragma unroll
        for (int kk = 0; kk < 40; kk += 4) {
            float4 a0 = *(float4*)&eT[r0 * 44 + kk];
            float4 a1 = *(float4*)&eT[r1 * 44 + kk];
#pragma unroll
            for (int i = 0; i < 19; ++i) {
                int j = jg + 8 * i;                        // <= 151, wT padded
                float4 w = *(float4*)&wT[j * 44 + kk];
                acc0[i] += a0.x * w.x + a0.y * w.y + a0.z * w.z + a0.w * w.w;
                acc1[i] += a1.x * w.x + a1.y * w.y + a1.z * w.z + a1.w * w.w;
            }
        }
    }
    __syncthreads();
#pragma unroll
    for (int i = 0; i < 19; ++i) {                         // stage to outT for coalesced write
        int j = jg + 8 * i;
        if (j < 150) { smem[r0 * 150 + j] = acc0[i]; smem[r1 * 150 + j] = acc1[i]; }
    }
    __syncthreads();
    float4* og = (float4*)(out + blockR * 150);
    for (int fid = t; fid < 2400; fid += 256)
        og[fid] = *(float4*)&smem[fid * 4];
}

// ---------------------------------------------------------------------------
// GRU scan: hs[r][t][h]; xp precomputed [R][T][150]. Block = 8 sequences.
// ---------------------------------------------------------------------------
__global__ __launch_bounds__(256) void k_gru_scan(
    const float* __restrict__ xp, const float* __restrict__ Whh,
    const float* __restrict__ bhh, float* __restrict__ hs, int T)
{
    __shared__ float whhT[50 * 160];   // [k][j], cols 150..159 garbage
    __shared__ float ghL[8 * 160];
    __shared__ float hL[8 * 52];
    const int t = threadIdx.x;
    for (int e = t; e < 7500; e += 256) {
        int k = e / 150, j = e % 150;
        whhT[k * 160 + j] = Whh[j * 50 + k];
    }
    for (int e = t; e < 8 * 52; e += 256) hL[e] = 0.f;

    const int s = t >> 5, jc = t & 31;
    const long seqbase = (long)blockIdx.x * 8;
    float bb[5];
#pragma unroll
    for (int i = 0; i < 5; ++i) {
        int j = jc + 32 * i;
        bb[i] = (j < 150) ? bhh[j] : 0.f;
    }
    __syncthreads();

    for (int st = 0; st < T; ++st) {
        float g[5] = { bb[0], bb[1], bb[2], bb[3], bb[4] };
#pragma unroll 10
        for (int k = 0; k < 50; ++k) {
            float hk = hL[s * 52 + k];                     // broadcast
#pragma unroll
            for (int i = 0; i < 5; ++i)
                g[i] += hk * whhT[k * 160 + jc + 32 * i];  // lane-stride-1, conflict-free
        }
#pragma unroll
        for (int i = 0; i < 5; ++i) ghL[s * 160 + jc + 32 * i] = g[i];
        __syncthreads();
        for (int item = t; item < 400; item += 256) {
            int ss = item / 50, hh = item % 50;
            const float* xr = xp + ((seqbase + ss) * T + st) * 150;
            float vr  = xr[hh]       + ghL[ss * 160 + hh];
            float vz  = xr[50 + hh]  + ghL[ss * 160 + 50 + hh];
            float ghn = ghL[ss * 160 + 100 + hh];
            float r = 1.f / (1.f + __expf(-vr));
            float z = 1.f / (1.f + __expf(-vz));
            float a = xr[100 + hh] + r * ghn;
            a = fminf(fmaxf(a, -15.f), 15.f);
            float e2 = __expf(-2.f * a);
            float n = (1.f - e2) / (1.f + e2);
            float hn = (1.f - z) * n + z * hL[ss * 52 + hh];
            hL[ss * 52 + hh] = hn;
            hs[((seqbase + ss) * T + st) * 50 + hh] = hn;
        }
        __syncthreads();
    }
}

// ---------------------------------------------------------------------------
// ctx_hA[r][k] = sum_j ctx_h[r][j] * A[j][k]   (R = B*T rows, 32 rows/block)
// ---------------------------------------------------------------------------
__global__ __launch_bounds__(256) void k_matA(
    const float* __restrict__ inp, const float* __restrict__ A,
    float* __restrict__ outp)
{
    __shared__ float AL[50 * 52];
    __shared__ float inL[32 * 52];
    const int t = threadIdx.x;
    for (int e = t; e < 2500; e += 256) AL[(e / 50) * 52 + (e % 50)] = A[e];
    const long rbase = (long)blockIdx.x * 32;
    for (int e = t; e < 1600; e += 256) {
        int r = e / 50, j = e % 50;
        inL[r * 52 + j] = inp[(rbase + r) * 50 + j];
    }
    __syncthreads();
    for (int item = t; item < 1600; item += 256) {
        int r = item / 50, kk = item % 50;
        float acc = 0.f;
#pragma unroll 10
        for (int j = 0; j < 50; ++j)
            acc += inL[r * 52 + j] * AL[j * 52 + kk];
        outp[(rbase + r) * 50 + kk] = acc;
    }
}

// ---------------------------------------------------------------------------
// Fused match (M1 or M2, both channels) + conv3x3 + maxpool3x3/3.
// Block per conv-input slot n (local to group). r = n%14:
//   r <  7 : channels = M1[c=2r], M1[c=2r+1]   (emb dot, K=200)
//   r >= 7 : channels = M2[c=2(r-7)], M2[...+1] (ctxA . candh, K=50)
// Epilogue writes feats_g[n_local][800].
// ---------------------------------------------------------------------------
__global__ __launch_bounds__(256) void k_matchconv(
    const float* __restrict__ emb, const int* __restrict__ ctx_idx,
    const int* __restrict__ cand_idx, const float* __restrict__ ctxA,
    const float* __restrict__ candh_g, const float* __restrict__ conv_w,
    float* __restrict__ feats_g, int b0)
{
    __shared__ float M[2][1024];
    __shared__ float wL[144];
    __shared__ float pool[3 * 32 * 104];   // M1: ctxL[32][104] + canL[2][32][104]; M2 uses prefix
    __shared__ int ci[32], qi[2][32];
    const int t = threadIdx.x;
    const int nl = blockIdx.x;
    const int bl = nl / 14, r = nl % 14;
    const int b = b0 + bl;
    const int q = t & 31, pb = t >> 5;
    float acc[2][4] = { {0,0,0,0}, {0,0,0,0} };

    if (t < 144) wL[t] = conv_w[t];

    if (r < 7) {
        const int c0 = 2 * r;
        if (t < 32) ci[t] = ctx_idx[b * 32 + t];
        else if (t < 96)
            qi[(t - 32) >> 5][t & 31] =
                cand_idx[((long)b * 14 + c0 + ((t - 32) >> 5)) * 32 + (t & 31)];
        float* ctxL = pool;                  // [32][104]
        float* canL = pool + 32 * 104;       // [2][32][104]
        for (int kc = 0; kc < 200; kc += 100) {
            __syncthreads();
            for (int fid = t; fid < 2400; fid += 256) {
                int mat = fid / 800, rr = (fid % 800) / 25, k4 = fid % 25;
                int row = (mat == 0) ? ci[rr] : qi[mat - 1][rr];
                float4 v = *(const float4*)(emb + (size_t)row * 200 + kc + k4 * 4);
                float* dst = (mat == 0) ? &ctxL[rr * 104 + k4 * 4]
                                        : &canL[((mat - 1) * 32 + rr) * 104 + k4 * 4];
                *(float4*)dst = v;
            }
            __syncthreads();
            for (int k4 = 0; k4 < 25; ++k4) {
                float4 cq0 = *(float4*)&canL[q * 104 + k4 * 4];
                float4 cq1 = *(float4*)&canL[(32 + q) * 104 + k4 * 4];
#pragma unroll
                for (int i = 0; i < 4; ++i) {
                    float4 cp = *(float4*)&ctxL[(pb + 8 * i) * 104 + k4 * 4];  // broadcast
                    acc[0][i] += cp.x * cq0.x + cp.y * cq0.y + cp.z * cq0.z + cp.w * cq0.w;
                    acc[1][i] += cp.x * cq1.x + cp.y * cq1.y + cp.z * cq1.z + cp.w * cq1.w;
                }
            }
        }
    } else {
        const int c0 = 2 * (r - 7);
        float* aL = pool;               // [32][53]
        float* cL = pool + 32 * 53;     // [2][32][53]
        for (int e = t; e < 1600; e += 256) {
            int rr = e / 50, k = e % 50;
            aL[rr * 53 + k] = ctxA[((long)b * 32 + rr) * 50 + k];
            cL[rr * 53 + k]        = candh_g[(((long)bl * 14 + c0) * 32 + rr) * 50 + k];
            cL[(32 + rr) * 53 + k] = candh_g[(((long)bl * 14 + c0 + 1) * 32 + rr) * 50 + k];
        }
        __syncthreads();
#pragma unroll 10
        for (int k = 0; k < 50; ++k) {
            float cq0 = cL[q * 53 + k];
            float cq1 = cL[(32 + q) * 53 + k];
#pragma unroll
            for (int i = 0; i < 4; ++i) {
                float a = aL[(pb + 8 * i) * 53 + k];       // broadcast
                acc[0][i] += a * cq0;
                acc[1][i] += a * cq1;
            }
        }
    }

#pragma unroll
    for (int i = 0; i < 4; ++i) {
        M[0][(pb + 8 * i) * 32 + q] = acc[0][i];
        M[1][(pb + 8 * i) * 32 + q] = acc[1][i];
    }
    __syncthreads();

    for (int item = t; item < 800; item += 256) {
        int oc = item / 100, rem = item % 100, py = rem / 10, px = rem % 10;
        float pv[2][5][5];
#pragma unroll
        for (int ch = 0; ch < 2; ++ch)
#pragma unroll
            for (int dy = 0; dy < 5; ++dy)
#pragma unroll
                for (int dx = 0; dx < 5; ++dx)
                    pv[ch][dy][dx] = M[ch][(3 * py + dy) * 32 + (3 * px + dx)];
        float m = -1e30f;
#pragma unroll
        for (int dy0 = 0; dy0 < 3; ++dy0)
#pragma unroll
            for (int dx0 = 0; dx0 < 3; ++dx0) {
                float sacc = 0.f;
#pragma unroll
                for (int ch = 0; ch < 2; ++ch)
#pragma unroll
                    for (int ky = 0; ky < 3; ++ky)
#pragma unroll
                        for (int kx = 0; kx < 3; ++kx)
                            sacc += pv[ch][dy0 + ky][dx0 + kx] * wL[(oc * 2 + ch) * 9 + ky * 3 + kx];
                m = fmaxf(m, sacc);
            }
        feats_g[(long)nl * 800 + item] = m;
    }
}

// ---------------------------------------------------------------------------
// fc1: hid[b][o] = relu(dot(Hs[b][0:700], fc1_w[o]) + fc1_b[o])
// ---------------------------------------------------------------------------
__global__ __launch_bounds__(128) void k_fc1(
    const float* __restrict__ Hs, const float* __restrict__ w,
    const float* __restrict__ bias, float* __restrict__ hid)
{
    __shared__ float hr[700];
    const int t = threadIdx.x;
    const long b = blockIdx.x;
    for (int e = t; e < 700; e += 128) hr[e] = Hs[b * 700 + e];
    __syncthreads();
    if (t < 100) {
        float acc = bias[t];
        const float4* wp = (const float4*)(w + (size_t)t * 700);
        for (int k4 = 0; k4 < 175; ++k4) {
            float4 wv = wp[k4];
            float4 hv = *(float4*)&hr[k4 * 4];
            acc += wv.x * hv.x + wv.y * hv.y + wv.z * hv.z + wv.w * hv.w;
        }
        hid[b * 100 + t] = fmaxf(acc, 0.f);
    }
}

// ---------------------------------------------------------------------------
// fc2 + log_softmax + KL per b -> partial[b]. One wave per b.
// ---------------------------------------------------------------------------
__global__ __launch_bounds__(64) void k_final(
    const float* __restrict__ hid, const float* __restrict__ w2,
    const float* __restrict__ b2, const float* __restrict__ y,
    float* __restrict__ partial)
{
    __shared__ float hL[100];
    const int t = threadIdx.x;
    const long b = blockIdx.x;
    for (int e = t; e < 100; e += 64) hL[e] = hid[b * 100 + e];
    __syncthreads();
    float logit = -1e30f;
    if (t < 14) {
        logit = b2[t];
        for (int k = 0; k < 100; ++k) logit += hL[k] * w2[t * 100 + k];
    }
    float m = logit;
    for (int off = 8; off; off >>= 1) m = fmaxf(m, __shfl_xor(m, off, 16));
    float ex = (t < 14) ? __expf(logit - m) : 0.f;
    float se = ex;
    for (int off = 8; off; off >>= 1) se += __shfl_xor(se, off, 16);
    float kl = 0.f;
    if (t < 14) {
        float lp = logit - m - __logf(se);
        float yv = y[b * 14 + t];
        kl = (yv > 0.f) ? yv * (__logf(yv) - lp) : 0.f;
    }
    for (int off = 8; off; off >>= 1) kl += __shfl_xor(kl, off, 16);
    if (t == 0) partial[b] = kl;
}

__global__ __launch_bounds__(256) void k_reduce(
    const float* __restrict__ partial, float* __restrict__ out)
{
    __shared__ float sm[256];
    const int t = threadIdx.x;
    sm[t] = partial[t] + partial[t + 256] + partial[t + 512] + partial[t + 768];
    __syncthreads();
    for (int off = 128; off; off >>= 1) {
        if (t < off) sm[t] += sm[t + off];
        __syncthreads();
    }
    if (t == 0) out[0] = sm[0] * (1.f / 14336.f);
}

// ---------------------------------------------------------------------------
extern "C" void kernel_launch(void* const* d_in, const int* in_sizes, int n_in,
                              void* d_out, int out_size, void* d_ws, size_t ws_size,
                              hipStream_t stream)
{
    const int*   ctx_idx  = (const int*)d_in[0];
    const int*   cand_idx = (const int*)d_in[1];
    const float* y_dev    = (const float*)d_in[2];
    const float* emb      = (const float*)d_in[3];
    const float* A        = (const float*)d_in[4];
    const float* Wih_c    = (const float*)d_in[5];
    const float* Whh_c    = (const float*)d_in[6];
    const float* bih_c    = (const float*)d_in[7];
    const float* bhh_c    = (const float*)d_in[8];
    const float* Wih_r    = (const float*)d_in[9];
    const float* Whh_r    = (const float*)d_in[10];
    const float* bih_r    = (const float*)d_in[11];
    const float* bhh_r    = (const float*)d_in[12];
    const float* conv_w   = (const float*)d_in[13];
    const float* Wih2     = (const float*)d_in[14];
    const float* Whh2     = (const float*)d_in[15];
    const float* bih2     = (const float*)d_in[16];
    const float* bhh2     = (const float*)d_in[17];
    const float* fc1_w    = (const float*)d_in[18];
    const float* fc1_b    = (const float*)d_in[19];
    const float* fc2_w    = (const float*)d_in[20];
    const float* fc2_b    = (const float*)d_in[21];

    float* ws = (float*)d_ws;
    // Fixed (persistent) buffers — 6,247,424 floats = 25 MB
    float* ctx_h = ws;                       // [1024*32][50]  = 1,638,400
    float* ctxA  = ws + 1638400;             // [1024*32][50]  = 1,638,400
    float* hs2   = ws + 3276800;             // [1024][14][50] =   716,800
    float* hid   = ws + 3993600;             // [1024][100]    =   102,400
    float* part  = ws + 4096000;             // [1024]         =     1,024
    float* xp2   = ws + 4097024;             // [14336][150]   = 2,150,400
    float* grp   = ws + 6247424;             // group arena starts here

    // Pick smallest group count G whose arena fits ws_size (deterministic).
    const long Gopts[5] = { 1, 2, 4, 8, 16 };
    long G = 16;
    for (int gi = 0; gi < 5; ++gi) {
        long BGc = 1024 / Gopts[gi];
        long xpn = BGc * 67200;                               // cand xp chunk
        if (xpn < 4915200) xpn = 4915200;                     // ctx xp floor
        long need = 6247424 + BGc * 11200 + BGc * 22400 + xpn;
        if ((size_t)need * 4 <= ws_size) { G = Gopts[gi]; break; }
    }
    const long BG = 1024 / G;
    float* feats_g = grp;                     // [BG*14][800]
    float* candh_g = feats_g + BG * 11200;    // [BG*14*32][50]
    float* xp_buf  = candh_g + BG * 22400;    // max(ctx xp, cand chunk xp, xp2 slice)

    // Context path (once)
    k_gemm150 <<<512, 256, 0, stream>>>(Wih_c, bih_c, emb, ctx_idx, xp_buf, 200);
    k_gru_scan<<<128, 256, 0, stream>>>(xp_buf, Whh_c, bhh_c, ctx_h, 32);
    k_matA    <<<1024, 256, 0, stream>>>(ctx_h, A, ctxA);

    // Candidate path, grouped
    for (long g = 0; g < G; ++g) {
        const int b0 = (int)(g * BG);
        const int* cidx_g = cand_idx + (long)b0 * 14 * 32;
        k_gemm150  <<<BG * 7, 256, 0, stream>>>(Wih_r, bih_r, emb, cidx_g, xp_buf, 200);
        k_gru_scan <<<BG * 14 / 8, 256, 0, stream>>>(xp_buf, Whh_r, bhh_r, candh_g, 32);
        k_matchconv<<<BG * 14, 256, 0, stream>>>(emb, ctx_idx, cand_idx, ctxA, candh_g,
                                                 conv_w, feats_g, b0);
        k_gemm150  <<<BG * 14 / 64, 256, 0, stream>>>(Wih2, bih2, feats_g, nullptr,
                                                      xp2 + (long)b0 * 14 * 150, 800);
        k_gru_scan <<<BG / 8, 256, 0, stream>>>(xp2 + (long)b0 * 14 * 150, Whh2, bhh2,
                                                hs2 + (long)b0 * 700, 14);
    }

    // Head
    k_fc1   <<<1024, 128, 0, stream>>>(hs2, fc1_w, fc1_b, hid);
    k_final <<<1024, 64, 0, stream>>>(hid, fc2_w, fc2_b, y_dev, part);
    k_reduce<<<1, 256, 0, stream>>>(part, (float*)d_out);
}

// Round 4
// 1357.063 us; speedup vs baseline: 2.0304x; 2.0304x over previous
//
#include <hip/hip_runtime.h>
#include <math.h>

// ---------------------------------------------------------------------------
// Vocab projection: out[v][j] = dot(emb[v], W[j]) + bias[j], j<150, stride 152.
// Blocks of 64 rows; source row clamped to V-1 (writes land in padding rows).
// ---------------------------------------------------------------------------
__global__ __launch_bounds__(256) void k_proj(
    const float* __restrict__ W, const float* __restrict__ bias,
    const float* __restrict__ emb, float* __restrict__ out, int K, int V)
{
    __shared__ float smem[9728];               // eT[64][44] | wT[152][44] -> outT[64][152]
    __shared__ const float* rptr[64];
    float* eT = smem;
    float* wT = smem + 64 * 44;
    const int t = threadIdx.x;
    const long blockR = (long)blockIdx.x * 64;

    if (t < 64) {
        long gr = blockR + t;
        if (gr >= V) gr = V - 1;
        rptr[t] = emb + (size_t)gr * (size_t)K;
    }

    const int r0 = t & 31;
    const int r1 = r0 + 32;
    const int jg = t >> 5;

    float acc0[19], acc1[19];
#pragma unroll
    for (int i = 0; i < 19; ++i) {
        int j = jg + 8 * i;
        float b = (j < 150) ? bias[j] : 0.f;
        acc0[i] = b; acc1[i] = b;
    }

    const int nch = K / 40;
    for (int c = 0; c < nch; ++c) {
        const int k0 = c * 40;
        __syncthreads();
        for (int fid = t; fid < 640; fid += 256) {
            int r = fid / 10, ko = (fid % 10) * 4;
            *(float4*)&eT[r * 44 + ko] = *(const float4*)(rptr[r] + k0 + ko);
        }
        for (int fid = t; fid < 1500; fid += 256) {
            int r = fid / 10, ko = (fid % 10) * 4;
            *(float4*)&wT[r * 44 + ko] = *(const float4*)(W + (size_t)r * K + k0 + ko);
        }
        __syncthreads();
#pragma unroll
        for (int kk = 0; kk < 40; kk += 4) {
            float4 a0 = *(float4*)&eT[r0 * 44 + kk];
            float4 a1 = *(float4*)&eT[r1 * 44 + kk];
#pragma unroll
            for (int i = 0; i < 19; ++i) {
                int j = jg + 8 * i;
                float4 w = *(float4*)&wT[j * 44 + kk];
                acc0[i] += a0.x * w.x + a0.y * w.y + a0.z * w.z + a0.w * w.w;
                acc1[i] += a1.x * w.x + a1.y * w.y + a1.z * w.z + a1.w * w.w;
            }
        }
    }
    __syncthreads();
#pragma unroll
    for (int i = 0; i < 19; ++i) {
        int j = jg + 8 * i;
        if (j < 150) { smem[r0 * 152 + j] = acc0[i]; smem[r1 * 152 + j] = acc1[i]; }
    }
    __syncthreads();
    float4* og = (float4*)(out + blockR * 152);
    for (int fid = t; fid < 2432; fid += 256)
        og[fid] = *(float4*)&smem[fid * 4];
}

// ---------------------------------------------------------------------------
// Generic GEMM (direct rows): out[r][j] (stride 152) = dot(src[r], W[j]) + b[j]
// ---------------------------------------------------------------------------
__global__ __launch_bounds__(256) void k_gemm150(
    const float* __restrict__ W, const float* __restrict__ bias,
    const float* __restrict__ src, float* __restrict__ out, int K)
{
    __shared__ float smem[9728];
    __shared__ const float* rptr[64];
    float* eT = smem;
    float* wT = smem + 64 * 44;
    const int t = threadIdx.x;
    const long blockR = (long)blockIdx.x * 64;

    if (t < 64) rptr[t] = src + (size_t)(blockR + t) * (size_t)K;

    const int r0 = t & 31;
    const int r1 = r0 + 32;
    const int jg = t >> 5;

    float acc0[19], acc1[19];
#pragma unroll
    for (int i = 0; i < 19; ++i) {
        int j = jg + 8 * i;
        float b = (j < 150) ? bias[j] : 0.f;
        acc0[i] = b; acc1[i] = b;
    }

    const int nch = K / 40;
    for (int c = 0; c < nch; ++c) {
        const int k0 = c * 40;
        __syncthreads();
        for (int fid = t; fid < 640; fid += 256) {
            int r = fid / 10, ko = (fid % 10) * 4;
            *(float4*)&eT[r * 44 + ko] = *(const float4*)(rptr[r] + k0 + ko);
        }
        for (int fid = t; fid < 1500; fid += 256) {
            int r = fid / 10, ko = (fid % 10) * 4;
            *(float4*)&wT[r * 44 + ko] = *(const float4*)(W + (size_t)r * K + k0 + ko);
        }
        __syncthreads();
#pragma unroll
        for (int kk = 0; kk < 40; kk += 4) {
            float4 a0 = *(float4*)&eT[r0 * 44 + kk];
            float4 a1 = *(float4*)&eT[r1 * 44 + kk];
#pragma unroll
            for (int i = 0; i < 19; ++i) {
                int j = jg + 8 * i;
                float4 w = *(float4*)&wT[j * 44 + kk];
                acc0[i] += a0.x * w.x + a0.y * w.y + a0.z * w.z + a0.w * w.w;
                acc1[i] += a1.x * w.x + a1.y * w.y + a1.z * w.z + a1.w * w.w;
            }
        }
    }
    __syncthreads();
#pragma unroll
    for (int i = 0; i < 19; ++i) {
        int j = jg + 8 * i;
        if (j < 150) { smem[r0 * 152 + j] = acc0[i]; smem[r1 * 152 + j] = acc1[i]; }
    }
    __syncthreads();
    float4* og = (float4*)(out + blockR * 152);
    for (int fid = t; fid < 2432; fid += 256)
        og[fid] = *(float4*)&smem[fid * 4];
}

// ---------------------------------------------------------------------------
// GRU scan, fused x-gather. xp rows stride 152 (bih pre-folded for gather mode).
// idx != null: row = idx[seq*T+st]; idx == null: row = seq*T+st.
// 8 seqs/block; double-buffered LDS prefetch of next step's x rows.
// ---------------------------------------------------------------------------
__global__ __launch_bounds__(256) void k_gru_scan(
    const float* __restrict__ xp, const int* __restrict__ idx,
    const float* __restrict__ Whh, const float* __restrict__ bhh,
    float* __restrict__ hs, int T)
{
    __shared__ float whhT[50 * 160];   // [k][j], j<150 valid
    __shared__ float ghL[8 * 160];
    __shared__ float hL[8 * 52];
    __shared__ float xbuf[2][8 * 152];
    const int t = threadIdx.x;
    for (int e = t; e < 7500; e += 256) {
        int k = e / 150, j = e % 150;
        whhT[k * 160 + j] = Whh[j * 50 + k];
    }
    for (int e = t; e < 8 * 52; e += 256) hL[e] = 0.f;

    const int s = t >> 5, jc = t & 31;
    const long seqbase = (long)blockIdx.x * 8;
    float4 bb4 = *(const float4*)(bhh + 4 * jc);
    float bt = (jc < 22) ? bhh[128 + jc] : 0.f;

    // prefetch mapping: 8 rows x 38 float4 = 304 items; thread t -> {t, t+256}
    const int rA = t / 38, oA = (t % 38) * 4;
    const int rB = (t + 256) / 38, oB = ((t + 256) % 38) * 4;
    const bool hasB = (t < 48);

#define ROWP(rr, stp) (idx ? (xp + (size_t)idx[(seqbase + (rr)) * T + (stp)] * 152) \
                           : (xp + ((size_t)(seqbase + (rr)) * T + (stp)) * 152))

    *(float4*)&xbuf[0][rA * 152 + oA] = *(const float4*)(ROWP(rA, 0) + oA);
    if (hasB) *(float4*)&xbuf[0][rB * 152 + oB] = *(const float4*)(ROWP(rB, 0) + oB);
    __syncthreads();

    for (int st = 0; st < T; ++st) {
        const int cur = st & 1;
        float4 pf0, pf1;
        if (st + 1 < T) {
            pf0 = *(const float4*)(ROWP(rA, st + 1) + oA);
            if (hasB) pf1 = *(const float4*)(ROWP(rB, st + 1) + oB);
        }
        // GEMV: g[j] = bhh[j] + sum_k h[k] * Whh[j][k]
        float4 g4 = bb4; float gt = bt;
#pragma unroll 10
        for (int k = 0; k < 50; ++k) {
            float hk = hL[s * 52 + k];                       // broadcast
            float4 w4 = *(float4*)&whhT[k * 160 + 4 * jc];   // conflict-lite b128
            g4.x += hk * w4.x; g4.y += hk * w4.y;
            g4.z += hk * w4.z; g4.w += hk * w4.w;
            if (jc < 22) gt += hk * whhT[k * 160 + 128 + jc];
        }
        *(float4*)&ghL[s * 160 + 4 * jc] = g4;
        if (jc < 22) ghL[s * 160 + 128 + jc] = gt;
        __syncthreads();
        // stash prefetched rows for st+1 (disjoint buffer from xbuf[cur])
        if (st + 1 < T) {
            *(float4*)&xbuf[cur ^ 1][rA * 152 + oA] = pf0;
            if (hasB) *(float4*)&xbuf[cur ^ 1][rB * 152 + oB] = pf1;
        }
        // activation + state update
        for (int item = t; item < 400; item += 256) {
            int ss = item / 50, hh = item % 50;
            const float* xr = &xbuf[cur][ss * 152];
            float vr  = xr[hh]       + ghL[ss * 160 + hh];
            float vz  = xr[50 + hh]  + ghL[ss * 160 + 50 + hh];
            float ghn = ghL[ss * 160 + 100 + hh];
            float r = 1.f / (1.f + __expf(-vr));
            float z = 1.f / (1.f + __expf(-vz));
            float a = xr[100 + hh] + r * ghn;
            a = fminf(fmaxf(a, -15.f), 15.f);
            float e2 = __expf(-2.f * a);
            float n = (1.f - e2) / (1.f + e2);
            float hn = (1.f - z) * n + z * hL[ss * 52 + hh];
            hL[ss * 52 + hh] = hn;
            hs[((seqbase + ss) * T + st) * 50 + hh] = hn;
        }
        __syncthreads();
    }
#undef ROWP
}

// ---------------------------------------------------------------------------
// ctx_hA[r][k] = sum_j ctx_h[r][j] * A[j][k]
// ---------------------------------------------------------------------------
__global__ __launch_bounds__(256) void k_matA(
    const float* __restrict__ inp, const float* __restrict__ A,
    float* __restrict__ outp)
{
    __shared__ float AL[50 * 52];
    __shared__ float inL[32 * 52];
    const int t = threadIdx.x;
    for (int e = t; e < 2500; e += 256) AL[(e / 50) * 52 + (e % 50)] = A[e];
    const long rbase = (long)blockIdx.x * 32;
    for (int e = t; e < 1600; e += 256) {
        int r = e / 50, j = e % 50;
        inL[r * 52 + j] = inp[(rbase + r) * 50 + j];
    }
    __syncthreads();
    for (int item = t; item < 1600; item += 256) {
        int r = item / 50, kk = item % 50;
        float acc = 0.f;
#pragma unroll 10
        for (int j = 0; j < 50; ++j)
            acc += inL[r * 52 + j] * AL[j * 52 + kk];
        outp[(rbase + r) * 50 + kk] = acc;
    }
}

// ---------------------------------------------------------------------------
// Fused match (M1 or M2, both channels) + conv3x3 + maxpool3x3/3.
// ---------------------------------------------------------------------------
__global__ __launch_bounds__(256) void k_matchconv(
    const float* __restrict__ emb, const int* __restrict__ ctx_idx,
    const int* __restrict__ cand_idx, const float* __restrict__ ctxA,
    const float* __restrict__ candh_g, const float* __restrict__ conv_w,
    float* __restrict__ feats_g, int b0)
{
    __shared__ float M[2][1024];
    __shared__ float wL[144];
    __shared__ float pool[3 * 32 * 104];
    __shared__ int ci[32], qi[2][32];
    const int t = threadIdx.x;
    const int nl = blockIdx.x;
    const int bl = nl / 14, r = nl % 14;
    const int b = b0 + bl;
    const int q = t & 31, pb = t >> 5;
    float acc[2][4] = { {0,0,0,0}, {0,0,0,0} };

    if (t < 144) wL[t] = conv_w[t];

    if (r < 7) {
        const int c0 = 2 * r;
        if (t < 32) ci[t] = ctx_idx[b * 32 + t];
        else if (t < 96)
            qi[(t - 32) >> 5][t & 31] =
                cand_idx[((long)b * 14 + c0 + ((t - 32) >> 5)) * 32 + (t & 31)];
        float* ctxL = pool;
        float* canL = pool + 32 * 104;
        for (int kc = 0; kc < 200; kc += 100) {
            __syncthreads();
            for (int fid = t; fid < 2400; fid += 256) {
                int mat = fid / 800, rr = (fid % 800) / 25, k4 = fid % 25;
                int row = (mat == 0) ? ci[rr] : qi[mat - 1][rr];
                float4 v = *(const float4*)(emb + (size_t)row * 200 + kc + k4 * 4);
                float* dst = (mat == 0) ? &ctxL[rr * 104 + k4 * 4]
                                        : &canL[((mat - 1) * 32 + rr) * 104 + k4 * 4];
                *(float4*)dst = v;
            }
            __syncthreads();
            for (int k4 = 0; k4 < 25; ++k4) {
                float4 cq0 = *(float4*)&canL[q * 104 + k4 * 4];
                float4 cq1 = *(float4*)&canL[(32 + q) * 104 + k4 * 4];
#pragma unroll
                for (int i = 0; i < 4; ++i) {
                    float4 cp = *(float4*)&ctxL[(pb + 8 * i) * 104 + k4 * 4];
                    acc[0][i] += cp.x * cq0.x + cp.y * cq0.y + cp.z * cq0.z + cp.w * cq0.w;
                    acc[1][i] += cp.x * cq1.x + cp.y * cq1.y + cp.z * cq1.z + cp.w * cq1.w;
                }
            }
        }
    } else {
        const int c0 = 2 * (r - 7);
        float* aL = pool;
        float* cL = pool + 32 * 53;
        for (int e = t; e < 1600; e += 256) {
            int rr = e / 50, k = e % 50;
            aL[rr * 53 + k] = ctxA[((long)b * 32 + rr) * 50 + k];
            cL[rr * 53 + k]        = candh_g[(((long)bl * 14 + c0) * 32 + rr) * 50 + k];
            cL[(32 + rr) * 53 + k] = candh_g[(((long)bl * 14 + c0 + 1) * 32 + rr) * 50 + k];
        }
        __syncthreads();
#pragma unroll 10
        for (int k = 0; k < 50; ++k) {
            float cq0 = cL[q * 53 + k];
            float cq1 = cL[(32 + q) * 53 + k];
#pragma unroll
            for (int i = 0; i < 4; ++i) {
                float a = aL[(pb + 8 * i) * 53 + k];
                acc[0][i] += a * cq0;
                acc[1][i] += a * cq1;
            }
        }
    }

#pragma unroll
    for (int i = 0; i < 4; ++i) {
        M[0][(pb + 8 * i) * 32 + q] = acc[0][i];
        M[1][(pb + 8 * i) * 32 + q] = acc[1][i];
    }
    __syncthreads();

    for (int item = t; item < 800; item += 256) {
        int oc = item / 100, rem = item % 100, py = rem / 10, px = rem % 10;
        float pv[2][5][5];
#pragma unroll
        for (int ch = 0; ch < 2; ++ch)
#pragma unroll
            for (int dy = 0; dy < 5; ++dy)
#pragma unroll
                for (int dx = 0; dx < 5; ++dx)
                    pv[ch][dy][dx] = M[ch][(3 * py + dy) * 32 + (3 * px + dx)];
        float m = -1e30f;
#pragma unroll
        for (int dy0 = 0; dy0 < 3; ++dy0)
#pragma unroll
            for (int dx0 = 0; dx0 < 3; ++dx0) {
                float sacc = 0.f;
#pragma unroll
                for (int ch = 0; ch < 2; ++ch)
#pragma unroll
                    for (int ky = 0; ky < 3; ++ky)
#pragma unroll
                        for (int kx = 0; kx < 3; ++kx)
                            sacc += pv[ch][dy0 + ky][dx0 + kx] * wL[(oc * 2 + ch) * 9 + ky * 3 + kx];
                m = fmaxf(m, sacc);
            }
        feats_g[(long)nl * 800 + item] = m;
    }
}

// ---------------------------------------------------------------------------
__global__ __launch_bounds__(128) void k_fc1(
    const float* __restrict__ Hs, const float* __restrict__ w,
    const float* __restrict__ bias, float* __restrict__ hid)
{
    __shared__ float hr[700];
    const int t = threadIdx.x;
    const long b = blockIdx.x;
    for (int e = t; e < 700; e += 128) hr[e] = Hs[b * 700 + e];
    __syncthreads();
    if (t < 100) {
        float acc = bias[t];
        const float4* wp = (const float4*)(w + (size_t)t * 700);
        for (int k4 = 0; k4 < 175; ++k4) {
            float4 wv = wp[k4];
            float4 hv = *(float4*)&hr[k4 * 4];
            acc += wv.x * hv.x + wv.y * hv.y + wv.z * hv.z + wv.w * hv.w;
        }
        hid[b * 100 + t] = fmaxf(acc, 0.f);
    }
}

__global__ __launch_bounds__(64) void k_final(
    const float* __restrict__ hid, const float* __restrict__ w2,
    const float* __restrict__ b2, const float* __restrict__ y,
    float* __restrict__ partial)
{
    __shared__ float hL[100];
    const int t = threadIdx.x;
    const long b = blockIdx.x;
    for (int e = t; e < 100; e += 64) hL[e] = hid[b * 100 + e];
    __syncthreads();
    float logit = -1e30f;
    if (t < 14) {
        logit = b2[t];
        for (int k = 0; k < 100; ++k) logit += hL[k] * w2[t * 100 + k];
    }
    float m = logit;
    for (int off = 8; off; off >>= 1) m = fmaxf(m, __shfl_xor(m, off, 16));
    float ex = (t < 14) ? __expf(logit - m) : 0.f;
    float se = ex;
    for (int off = 8; off; off >>= 1) se += __shfl_xor(se, off, 16);
    float kl = 0.f;
    if (t < 14) {
        float lp = logit - m - __logf(se);
        float yv = y[b * 14 + t];
        kl = (yv > 0.f) ? yv * (__logf(yv) - lp) : 0.f;
    }
    for (int off = 8; off; off >>= 1) kl += __shfl_xor(kl, off, 16);
    if (t == 0) partial[b] = kl;
}

__global__ __launch_bounds__(256) void k_reduce(
    const float* __restrict__ partial, float* __restrict__ out)
{
    __shared__ float sm[256];
    const int t = threadIdx.x;
    sm[t] = partial[t] + partial[t + 256] + partial[t + 512] + partial[t + 768];
    __syncthreads();
    for (int off = 128; off; off >>= 1) {
        if (t < off) sm[t] += sm[t + off];
        __syncthreads();
    }
    if (t == 0) out[0] = sm[0] * (1.f / 14336.f);
}

// ---------------------------------------------------------------------------
extern "C" void kernel_launch(void* const* d_in, const int* in_sizes, int n_in,
                              void* d_out, int out_size, void* d_ws, size_t ws_size,
                              hipStream_t stream)
{
    const int*   ctx_idx  = (const int*)d_in[0];
    const int*   cand_idx = (const int*)d_in[1];
    const float* y_dev    = (const float*)d_in[2];
    const float* emb      = (const float*)d_in[3];
    const float* A        = (const float*)d_in[4];
    const float* Wih_c    = (const float*)d_in[5];
    const float* Whh_c    = (const float*)d_in[6];
    const float* bih_c    = (const float*)d_in[7];
    const float* bhh_c    = (const float*)d_in[8];
    const float* Wih_r    = (const float*)d_in[9];
    const float* Whh_r    = (const float*)d_in[10];
    const float* bih_r    = (const float*)d_in[11];
    const float* bhh_r    = (const float*)d_in[12];
    const float* conv_w   = (const float*)d_in[13];
    const float* Wih2     = (const float*)d_in[14];
    const float* Whh2     = (const float*)d_in[15];
    const float* bih2     = (const float*)d_in[16];
    const float* bhh2     = (const float*)d_in[17];
    const float* fc1_w    = (const float*)d_in[18];
    const float* fc1_b    = (const float*)d_in[19];
    const float* fc2_w    = (const float*)d_in[20];
    const float* fc2_b    = (const float*)d_in[21];

    float* ws = (float*)d_ws;
    // Arena (floats), total 47,122,432 = 188.5 MB (fits: round-3 run proved >= 231 MB).
    float* proj_c = ws;                 // [21184][152] = 3,219,968  (V=21128 + clamp pad)
    float* proj_r = ws +  3219968;      // [21184][152] = 3,219,968
    float* ctx_h  = ws +  6439936;      // [1024*32][50] = 1,638,400
    float* ctxA   = ws +  8078336;      // [1024*32][50] = 1,638,400
    float* candh  = ws +  9716736;      // [14336*32][50] = 22,937,600
    float* feats  = ws + 32654336;      // [14336][800] = 11,468,800
    float* xp2    = ws + 44123136;      // [14336][152] = 2,179,072
    float* hs2    = ws + 46302208;      // [1024][14][50] = 716,800
    float* hid    = ws + 47019008;      // [1024][100] = 102,400
    float* part   = ws + 47121408;      // [1024]

    // 1. project vocab once (replaces the 458k-row gather-GEMMs; bih folded in)
    k_proj    <<<331, 256, 0, stream>>>(Wih_c, bih_c, emb, proj_c, 200, 21128);
    k_proj    <<<331, 256, 0, stream>>>(Wih_r, bih_r, emb, proj_r, 200, 21128);
    // 2. GRU scans gather xp rows straight from the L2/L3-resident proj tables
    k_gru_scan<<<128,  256, 0, stream>>>(proj_c, ctx_idx,  Whh_c, bhh_c, ctx_h, 32);
    k_gru_scan<<<1792, 256, 0, stream>>>(proj_r, cand_idx, Whh_r, bhh_r, candh, 32);
    k_matA    <<<1024, 256, 0, stream>>>(ctx_h, A, ctxA);
    // 3. match + conv + pool
    k_matchconv<<<14336, 256, 0, stream>>>(emb, ctx_idx, cand_idx, ctxA, candh,
                                           conv_w, feats, 0);
    // 4. accumulation GRU + head
    k_gemm150 <<<224, 256, 0, stream>>>(Wih2, bih2, feats, xp2, 800);
    k_gru_scan<<<128, 256, 0, stream>>>(xp2, nullptr, Whh2, bhh2, hs2, 14);
    k_fc1     <<<1024, 128, 0, stream>>>(hs2, fc1_w, fc1_b, hid);
    k_final   <<<1024, 64, 0, stream>>>(hid, fc2_w, fc2_b, y_dev, part);
    k_reduce  <<<1, 256, 0, stream>>>(part, (float*)d_out);
}